// Round 1
// baseline (294.654 us; speedup 1.0000x reference)
//
#include <hip/hip_runtime.h>

// SparseProjector: out[b, idx[j]] = tau[b, j] * w[j], rest zeros.
// Strategy: build inverse map inv[p] (-1 if inactive, else j), then one
// fully-coalesced gather pass over the 1 GiB output.

typedef int   iv4 __attribute__((ext_vector_type(4)));
typedef float fv4 __attribute__((ext_vector_type(4)));

__global__ void fill_inv_kernel(int* __restrict__ inv, int n4) {
    int t = blockIdx.x * blockDim.x + threadIdx.x;
    int stride = gridDim.x * blockDim.x;
    iv4 m = (iv4)(-1);
    for (int i = t; i < n4; i += stride)
        ((iv4*)inv)[i] = m;
}

__global__ void build_inv_kernel(const int* __restrict__ idx,
                                 int* __restrict__ inv, int na) {
    int j = blockIdx.x * blockDim.x + threadIdx.x;
    if (j < na) inv[idx[j]] = j;   // indices unique -> no race
}

// grid: (ceil(p/4/256), B). Each thread: 4 consecutive pixels of row b.
__global__ void gather_kernel(const float* __restrict__ tau,
                              const float* __restrict__ w,
                              const int* __restrict__ inv,
                              float* __restrict__ out,
                              int na, int p, int n4) {
    int p4 = blockIdx.x * blockDim.x + threadIdx.x;
    if (p4 >= n4) return;
    int b = blockIdx.y;
    const float* taub = tau + (size_t)b * (size_t)na;
    iv4 iv = ((const iv4*)inv)[p4];
    fv4 o;
    o.x = (iv.x >= 0) ? taub[iv.x] * w[iv.x] : 0.0f;
    o.y = (iv.y >= 0) ? taub[iv.y] * w[iv.y] : 0.0f;
    o.z = (iv.z >= 0) ? taub[iv.z] * w[iv.z] : 0.0f;
    o.w = (iv.w >= 0) ? taub[iv.w] * w[iv.w] : 0.0f;
    fv4* dst = (fv4*)(out + (size_t)b * (size_t)p) + p4;
    __builtin_nontemporal_store(o, dst);   // 1 GiB stream: keep L2 for inv/tau
}

// ---------- fallback path (only if ws_size too small for inv map) ----------
__global__ void zero_out_kernel(float* __restrict__ out, long long n4) {
    long long t = (long long)blockIdx.x * blockDim.x + threadIdx.x;
    long long stride = (long long)gridDim.x * blockDim.x;
    fv4 z = (fv4)(0.0f);
    for (long long i = t; i < n4; i += stride)
        __builtin_nontemporal_store(z, (fv4*)out + i);
}

__global__ void scatter_kernel(const float* __restrict__ tau,
                               const float* __restrict__ w,
                               const int* __restrict__ idx,
                               float* __restrict__ out,
                               int na, int p, int batch) {
    int j = blockIdx.x * blockDim.x + threadIdx.x;
    if (j >= na) return;
    int pix = idx[j];
    float ww = w[j];
    for (int b = 0; b < batch; ++b)
        out[(size_t)b * p + pix] = tau[(size_t)b * na + j] * ww;
}

extern "C" void kernel_launch(void* const* d_in, const int* in_sizes, int n_in,
                              void* d_out, int out_size, void* d_ws, size_t ws_size,
                              hipStream_t stream) {
    const float* tau = (const float*)d_in[0];
    const float* w   = (const float*)d_in[1];
    const int*   idx = (const int*)d_in[2];
    float* out = (float*)d_out;

    int na = in_sizes[1];                 // 65536
    int batch = in_sizes[0] / na;         // 256
    int p = (int)((long long)out_size / batch);  // 1048576

    if (ws_size >= (size_t)p * sizeof(int) && (p % 4) == 0) {
        int* inv = (int*)d_ws;
        int n4 = p / 4;
        fill_inv_kernel<<<dim3(1024), dim3(256), 0, stream>>>(inv, n4);
        build_inv_kernel<<<dim3((na + 255) / 256), dim3(256), 0, stream>>>(idx, inv, na);
        dim3 grid((n4 + 255) / 256, batch);
        gather_kernel<<<grid, dim3(256), 0, stream>>>(tau, w, inv, out, na, p, n4);
    } else {
        long long n4 = ((long long)out_size) / 4;
        zero_out_kernel<<<dim3(2048), dim3(256), 0, stream>>>(out, n4);
        scatter_kernel<<<dim3((na + 255) / 256), dim3(256), 0, stream>>>(
            tau, w, idx, out, na, p, batch);
    }
}

// Round 2
// 220.064 us; speedup vs baseline: 1.3389x; 1.3389x over previous
//
#include <hip/hip_runtime.h>

// SparseProjector: out[b, idx[j]] = tau[b, j] * w[j], rest zeros.
// R2: gather with row-loop. Each block owns 1024 consecutive pixels and
// 32 rows; inv map + weights are loaded ONCE into registers, inner loop
// is scattered tau loads (avg 1 active per 4 pixels) + coalesced NT store.

typedef int   iv4 __attribute__((ext_vector_type(4)));
typedef float fv4 __attribute__((ext_vector_type(4)));

__global__ void fill_inv_kernel(int* __restrict__ inv, int n4) {
    int t = blockIdx.x * blockDim.x + threadIdx.x;
    int stride = gridDim.x * blockDim.x;
    iv4 m = (iv4)(-1);
    for (int i = t; i < n4; i += stride)
        ((iv4*)inv)[i] = m;
}

__global__ void build_inv_kernel(const int* __restrict__ idx,
                                 int* __restrict__ inv, int na) {
    int j = blockIdx.x * blockDim.x + threadIdx.x;
    if (j < na) inv[idx[j]] = j;   // indices unique -> no race
}

// grid: (n4/256, ROW_GROUPS). Each thread: 4 consecutive pixels, rows_per_blk rows.
__global__ __launch_bounds__(256)
void gather_rows_kernel(const float* __restrict__ tau,
                        const float* __restrict__ w,
                        const int* __restrict__ inv,
                        float* __restrict__ out,
                        int na, int p, int n4,
                        int rows_per_blk, int batch) {
    int p4 = blockIdx.x * blockDim.x + threadIdx.x;
    if (p4 >= n4) return;

    iv4 iv = ((const iv4*)inv)[p4];          // read once, lives in VGPRs
    float w0 = (iv.x >= 0) ? w[iv.x] : 0.0f; // row-invariant weights, hoisted
    float w1 = (iv.y >= 0) ? w[iv.y] : 0.0f;
    float w2 = (iv.z >= 0) ? w[iv.z] : 0.0f;
    float w3 = (iv.w >= 0) ? w[iv.w] : 0.0f;

    int b0 = blockIdx.y * rows_per_blk;
    int bend = b0 + rows_per_blk;
    if (bend > batch) bend = batch;

    const float* taub = tau + (size_t)b0 * (size_t)na;
    fv4* dst = (fv4*)(out + (size_t)b0 * (size_t)p) + p4;
    int pq = p >> 2;

    #pragma unroll 4
    for (int b = b0; b < bend; ++b) {
        fv4 o;
        o.x = (iv.x >= 0) ? taub[iv.x] * w0 : 0.0f;
        o.y = (iv.y >= 0) ? taub[iv.y] * w1 : 0.0f;
        o.z = (iv.z >= 0) ? taub[iv.z] * w2 : 0.0f;
        o.w = (iv.w >= 0) ? taub[iv.w] * w3 : 0.0f;
        __builtin_nontemporal_store(o, dst);  // 1 GiB stream: don't pollute L2
        taub += na;
        dst += pq;
    }
}

// ---------- fallback path (only if ws_size too small for inv map) ----------
__global__ void zero_out_kernel(float* __restrict__ out, long long n4) {
    long long t = (long long)blockIdx.x * blockDim.x + threadIdx.x;
    long long stride = (long long)gridDim.x * blockDim.x;
    fv4 z = (fv4)(0.0f);
    for (long long i = t; i < n4; i += stride)
        __builtin_nontemporal_store(z, (fv4*)out + i);
}

__global__ void scatter_kernel(const float* __restrict__ tau,
                               const float* __restrict__ w,
                               const int* __restrict__ idx,
                               float* __restrict__ out,
                               int na, int p, int batch) {
    int j = blockIdx.x * blockDim.x + threadIdx.x;
    if (j >= na) return;
    int pix = idx[j];
    float ww = w[j];
    for (int b = 0; b < batch; ++b)
        out[(size_t)b * p + pix] = tau[(size_t)b * na + j] * ww;
}

extern "C" void kernel_launch(void* const* d_in, const int* in_sizes, int n_in,
                              void* d_out, int out_size, void* d_ws, size_t ws_size,
                              hipStream_t stream) {
    const float* tau = (const float*)d_in[0];
    const float* w   = (const float*)d_in[1];
    const int*   idx = (const int*)d_in[2];
    float* out = (float*)d_out;

    int na = in_sizes[1];                        // 65536
    int batch = in_sizes[0] / na;                // 256
    int p = (int)((long long)out_size / batch);  // 1048576

    if (ws_size >= (size_t)p * sizeof(int) && (p % 1024) == 0) {
        int* inv = (int*)d_ws;
        int n4 = p / 4;
        fill_inv_kernel<<<dim3(1024), dim3(256), 0, stream>>>(inv, n4);
        build_inv_kernel<<<dim3((na + 255) / 256), dim3(256), 0, stream>>>(idx, inv, na);

        const int ROW_GROUPS = 8;
        int rows_per_blk = (batch + ROW_GROUPS - 1) / ROW_GROUPS;  // 32
        dim3 grid(n4 / 256, ROW_GROUPS);
        gather_rows_kernel<<<grid, dim3(256), 0, stream>>>(
            tau, w, inv, out, na, p, n4, rows_per_blk, batch);
    } else {
        long long n4 = ((long long)out_size) / 4;
        zero_out_kernel<<<dim3(2048), dim3(256), 0, stream>>>(out, n4);
        scatter_kernel<<<dim3((na + 255) / 256), dim3(256), 0, stream>>>(
            tau, w, idx, out, na, p, batch);
    }
}